// Round 5
// baseline (656.806 us; speedup 1.0000x reference)
//
#include <hip/hip_runtime.h>
#include <hip/hip_bf16.h>
#include <stdint.h>

#define Bb 2
#define Ss 2048
#define Hh 4096
#define NHh 32
#define HDd 128
#define KVHh 2

typedef __attribute__((ext_vector_type(8))) short bf16x8;
typedef __attribute__((ext_vector_type(4))) float f32x4;
typedef __attribute__((ext_vector_type(16))) float f32x16;
typedef __attribute__((ext_vector_type(4))) unsigned int u32x4;
typedef unsigned short u16;
typedef unsigned int u32;
typedef unsigned long long u64;

__device__ __forceinline__ u16 f2b(float f) {
  union { float f; u32 u; } v; v.f = f;
  u32 r = v.u + 0x7fffu + ((v.u >> 16) & 1u);
  return (u16)(r >> 16);
}
__device__ __forceinline__ float b2f(u16 h) {
  union { u32 u; float f; } v; v.u = ((u32)h) << 16;
  return v.f;
}

__device__ __forceinline__ u32 cvtpk(float lo, float hi_) {
  u32 r;
  asm("v_cvt_pk_bf16_f32 %0, %1, %2" : "=v"(r) : "v"(lo), "v"(hi_));
  return r;
}
__device__ __forceinline__ void plswap(u32& x, u32& y) {
  asm volatile("v_permlane32_swap_b32 %0, %1" : "+v"(x), "+v"(y));
}

// async global->LDS, 16B per lane; LDS dest is wave-uniform base + lane*16
__device__ __forceinline__ void gload_lds16(const u16* g, u16* l) {
  __builtin_amdgcn_global_load_lds(
      (const __attribute__((address_space(1))) u32*)(uintptr_t)g,
      (__attribute__((address_space(3))) u32*)(u32)(uintptr_t)l,
      16, 0, 0);
}

// ---------------- f32 -> bf16 convert (vectorized) ----------------
__global__ void cvt_k(const float* __restrict__ in, u16* __restrict__ out, int n) {
  int i = blockIdx.x * blockDim.x + threadIdx.x;
  int idx = i * 4;
  if (idx >= n) return;
  float4 v = *(const float4*)&in[idx];
  u64 pack = (u64)f2b(v.x) | ((u64)f2b(v.y) << 16) |
             ((u64)f2b(v.z) << 32) | ((u64)f2b(v.w) << 48);
  *(u64*)&out[idx] = pack;
}

// ---------------- RoPE in-place on (B, nheads, S, HD) bf16 ----------------
__global__ void rope_k(u16* __restrict__ X, const float* __restrict__ rope, int nheads) {
  int i = blockIdx.x * blockDim.x + threadIdx.x;
  int p = i & 31;
  int s = (i >> 5) & (Ss - 1);
  int bh = i >> 16;
  if (bh >= Bb * nheads) return;
  int b = bh / nheads;
  size_t base = ((size_t)bh * Ss + s) * HDd + p * 2;
  u32 x01 = *(u32*)&X[base];
  float x0 = b2f((u16)(x01 & 0xffff));
  float x1 = b2f((u16)(x01 >> 16));
  float2 rc = *(const float2*)&rope[(((size_t)b * Ss + s) * 32 + p) * 2];
  float o0 = x0 * rc.x - x1 * rc.y;
  float o1 = x1 * rc.x + x0 * rc.y;
  u32 o = (u32)f2b(o0) | ((u32)f2b(o1) << 16);
  *(u32*)&X[base] = o;
}

// ---------------- 128x128 tile GEMM, BK=32, 4 waves, counted-vmcnt dbuf ----------------
// LDS 32KB (2buf x (A 8KB + B 8KB)) -> 4-5 blocks/CU co-resident: independent barrier
// groups hide each other's load latency (m97's documented mechanism).
// Swizzle: 16B-chunk c' = c ^ ((row>>1)&3) on BOTH stage-source and ds_read ->
// 16 lanes hit all 8 bank-slots exactly 2x (2-way = free, m136).
// vmcnt(4): only tile t's 4 stage-loads must land; tile t+1's stay in flight.
template <int KK>
__device__ __forceinline__ void stage_tile(const u16* __restrict__ gbase, u16* dst, int tid) {
#pragma unroll
  for (int li = 0; li < 2; ++li) {
    int t16 = li * 256 + tid;
    int rt = t16 >> 2, ct = t16 & 3;
    int cg = ct ^ ((rt >> 1) & 3);
    gload_lds16(gbase + (size_t)rt * KK + cg * 8, dst + t16 * 8);
  }
}

__device__ __forceinline__ bf16x8 frag128(const u16* buf, int row, int lk) {
  int ch = lk ^ ((row >> 1) & 3);
  return *(const bf16x8*)&buf[row * 32 + ch * 8];
}

template <int MM, int NN, int KK, int NBN, int EPI>
__global__ __launch_bounds__(256, 4) void gemm128(
    const u16* __restrict__ A, const u16* __restrict__ Bm,
    float* __restrict__ Cout, const float* __restrict__ bias,
    u16* __restrict__ Qb, u16* __restrict__ Kb, u16* __restrict__ Vb) {
  __shared__ u16 As[2][4096];
  __shared__ u16 Bs[2][4096];
  const int tid = threadIdx.x;
  const int wave = tid >> 6;
  const int lane = tid & 63;
  const int lr = lane & 15;
  const int lk = lane >> 4;
  const int wr = wave >> 1;
  const int wc = wave & 1;
  // XCD-aware bijective swizzle (grid % 8 == 0)
  const int nwg = gridDim.x;
  const int bid = blockIdx.x;
  const int idx = (bid & 7) * (nwg >> 3) + (bid >> 3);
  const int m0 = (idx / NBN) * 128;
  const int n0 = (idx % NBN) * 128;
  const int NT = KK / 32;

  f32x4 acc[4][4];
#pragma unroll
  for (int i = 0; i < 4; ++i)
#pragma unroll
    for (int j = 0; j < 4; ++j) acc[i][j] = (f32x4){0.f, 0.f, 0.f, 0.f};

  const u16* Ab = A + (size_t)m0 * KK;
  const u16* Bb_ = Bm + (size_t)n0 * KK;

  // prologue: stage tile 0, drain, sync
  stage_tile<KK>(Ab, &As[0][0], tid);
  stage_tile<KK>(Bb_, &Bs[0][0], tid);
  asm volatile("s_waitcnt vmcnt(0)");
  __syncthreads();

  int cur = 0;
  for (int t = 0; t < NT; ++t) {
    if (t + 1 < NT) {
      stage_tile<KK>(Ab + (t + 1) * 32, &As[cur ^ 1][0], tid);
      stage_tile<KK>(Bb_ + (t + 1) * 32, &Bs[cur ^ 1][0], tid);
      asm volatile("s_waitcnt vmcnt(4)");   // tile t landed; t+1 stays in flight
    } else {
      asm volatile("s_waitcnt vmcnt(0)");
    }
    __builtin_amdgcn_s_barrier();           // all waves' tile-t stages landed
    __builtin_amdgcn_sched_barrier(0);

    bf16x8 af[4], bf[4];
#pragma unroll
    for (int mi = 0; mi < 4; ++mi)
      af[mi] = frag128(&As[cur][0], wr * 64 + mi * 16 + lr, lk);
#pragma unroll
    for (int ni = 0; ni < 4; ++ni)
      bf[ni] = frag128(&Bs[cur][0], wc * 64 + ni * 16 + lr, lk);
    asm volatile("s_waitcnt lgkmcnt(0)");
    __builtin_amdgcn_sched_barrier(0);
    __builtin_amdgcn_s_setprio(1);
#pragma unroll
    for (int mi = 0; mi < 4; ++mi)
#pragma unroll
      for (int ni = 0; ni < 4; ++ni)
        acc[mi][ni] = __builtin_amdgcn_mfma_f32_16x16x32_bf16(af[mi], bf[ni], acc[mi][ni], 0, 0, 0);
    __builtin_amdgcn_s_setprio(0);
    __builtin_amdgcn_s_barrier();           // reads done before next overwrite of buf[cur]
    cur ^= 1;
  }

  if constexpr (EPI == 0) {
#pragma unroll
    for (int mi = 0; mi < 4; ++mi)
#pragma unroll
      for (int ni = 0; ni < 4; ++ni) {
        int col = n0 + wc * 64 + ni * 16 + lr;
        int rowb = m0 + wr * 64 + mi * 16 + lk * 4;
#pragma unroll
        for (int j = 0; j < 4; ++j)
          Cout[(size_t)(rowb + j) * NN + col] = acc[mi][ni][j];
      }
  } else {
#pragma unroll
    for (int ni = 0; ni < 4; ++ni) {
      int n = n0 + wc * 64 + ni * 16 + lr;
      float bv = bias[n];
#pragma unroll
      for (int mi = 0; mi < 4; ++mi) {
        int mb = m0 + wr * 64 + mi * 16 + lk * 4;
#pragma unroll
        for (int j = 0; j < 4; ++j) {
          int m = mb + j;
          int bb = m >> 11;
          int ss = m & 2047;
          u16 hv = f2b(acc[mi][ni][j] + bv);
          if (n < 4096) {
            Qb[(((size_t)bb * NHh + (n >> 7)) * Ss + ss) * HDd + (n & 127)] = hv;
          } else if (n < 4352) {
            int idx2 = n - 4096;
            Kb[(((size_t)bb * KVHh + (idx2 >> 7)) * Ss + ss) * HDd + (idx2 & 127)] = hv;
          } else {
            int idx2 = n - 4352;
            Vb[(((size_t)bb * KVHh + (idx2 >> 7)) * Ss + ss) * HDd + (idx2 & 127)] = hv;
          }
        }
      }
    }
  }
}

// ---------------- causal GQA flash attention, 8-wave 32x32 swapped-QK^T ----------------
__global__ __launch_bounds__(512, 2) void attn_k(
    const u16* __restrict__ Qb, const u16* __restrict__ Kb,
    const u16* __restrict__ Vb, u16* __restrict__ Ctx) {
  __shared__ u16 Kt[2][64 * 128];
  __shared__ u16 Vt[2][128 * 64];
  const int tid = threadIdx.x;
  const int w = tid >> 6;
  const int lane = tid & 63;
  const int l31 = lane & 31;
  const int hi = lane >> 5;
  const int qt = 7 - (int)blockIdx.x;
  const int h = blockIdx.y, b = blockIdx.z;
  const int qs = qt * 256;
  const int qw = qs + w * 32;
  const int hkv = h >> 4;
  const u16* Qp = Qb + ((size_t)(b * NHh + h)) * Ss * HDd;
  const u16* Kp = Kb + ((size_t)(b * KVHh + hkv)) * Ss * HDd;
  const u16* Vp = Vb + ((size_t)(b * KVHh + hkv)) * Ss * HDd;
  const int qrow = qw + l31;

  bf16x8 qf[8];
#pragma unroll
  for (int ds = 0; ds < 8; ++ds)
    qf[ds] = *(const bf16x8*)&Qp[(size_t)qrow * HDd + ds * 16 + hi * 8];

  f32x16 accO[4];
#pragma unroll
  for (int i = 0; i < 4; ++i)
#pragma unroll
    for (int r = 0; r < 16; ++r) accO[i][r] = 0.f;
  float m_r = -3.0e38f, l_r = 0.f;

  const float scale = 0.08838834764831845f;
  const float L2E = 1.4426950408889634f;
  const int nt = qs / 64 + 4;

  {
#pragma unroll
    for (int i = 0; i < 2; ++i) {
      int slot = w * 2 + i;
      int r = slot * 4 + (lane >> 4);
      int p = lane & 15;
      int gc = (p & 8) | ((p ^ r) & 7);
      gload_lds16(Kp + (size_t)r * HDd + gc * 8, &Kt[0][slot * 512]);
    }
    bf16x8 v0 = *(const bf16x8*)&Vp[(size_t)lane * HDd + w * 16];
    bf16x8 v1 = *(const bf16x8*)&Vp[(size_t)lane * HDd + w * 16 + 8];
    u32x4 sv = __builtin_bit_cast(u32x4, (lane & 1) ? v0 : v1);
    u32x4 rv;
    rv.x = __shfl_xor(sv.x, 1); rv.y = __shfl_xor(sv.y, 1);
    rv.z = __shfl_xor(sv.z, 1); rv.w = __shfl_xor(sv.w, 1);
    bf16x8 recv = __builtin_bit_cast(bf16x8, rv);
    int kvp = lane >> 1;
#pragma unroll
    for (int i = 0; i < 8; ++i) {
      int d = w * 16 + (lane & 1) * 8 + i;
      u16 lo = (lane & 1) ? (u16)recv[i] : (u16)v0[i];
      u16 hb = (lane & 1) ? (u16)v1[i] : (u16)recv[i];
      u32 val = (u32)lo | ((u32)hb << 16);
      int cp = (kvp >> 2) ^ (d & 7);
      *(u32*)&Vt[0][d * 64 + cp * 8 + (kvp & 3) * 2] = val;
    }
  }
  __syncthreads();

  for (int t = 0; t < nt; ++t) {
    const int j0 = t * 64;
    const int cur = t & 1;
    const bool havenext = (t + 1 < nt);
    bf16x8 nv0, nv1;
    if (havenext) {
      const int j1 = j0 + 64;
#pragma unroll
      for (int i = 0; i < 2; ++i) {
        int slot = w * 2 + i;
        int r = slot * 4 + (lane >> 4);
        int p = lane & 15;
        int gc = (p & 8) | ((p ^ r) & 7);
        gload_lds16(Kp + (size_t)(j1 + r) * HDd + gc * 8, &Kt[cur ^ 1][slot * 512]);
      }
      nv0 = *(const bf16x8*)&Vp[(size_t)(j1 + lane) * HDd + w * 16];
      nv1 = *(const bf16x8*)&Vp[(size_t)(j1 + lane) * HDd + w * 16 + 8];
    }

    if (j0 <= qw + 31) {
      f32x16 aS[2];
#pragma unroll
      for (int a = 0; a < 2; ++a)
#pragma unroll
        for (int r = 0; r < 16; ++r) aS[a][r] = 0.f;
#pragma unroll
      for (int kvb = 0; kvb < 2; ++kvb) {
        int r = kvb * 32 + l31;
#pragma unroll
        for (int ds = 0; ds < 8; ++ds) {
          int c = ds * 2 + hi;
          int cp = (c & 8) | ((c ^ r) & 7);
          bf16x8 kf = *(const bf16x8*)&Kt[cur][r * 128 + cp * 8];
          aS[kvb] = __builtin_amdgcn_mfma_f32_32x32x16_bf16(kf, qf[ds], aS[kvb], 0, 0, 0);
        }
      }
      const bool needmask = (j0 + 63 > qw);
      float mx = -3.0e38f;
#pragma unroll
      for (int a = 0; a < 2; ++a)
#pragma unroll
        for (int r = 0; r < 16; ++r) {
          float s = aS[a][r] * scale;
          if (needmask) {
            int kv = j0 + a * 32 + (r & 3) + 8 * (r >> 2) + 4 * hi;
            s = (kv > qrow) ? -3.0e38f : s;
          }
          aS[a][r] = s;
          mx = fmaxf(mx, s);
        }
      mx = fmaxf(mx, __shfl_xor(mx, 32));
      float mnew = fmaxf(m_r, mx);
      float corr = __builtin_amdgcn_exp2f((m_r - mnew) * L2E);
      float sum = 0.f;
#pragma unroll
      for (int a = 0; a < 2; ++a)
#pragma unroll
        for (int r = 0; r < 16; ++r) {
          float pe = __builtin_amdgcn_exp2f((aS[a][r] - mnew) * L2E);
          aS[a][r] = pe;
          sum += pe;
        }
      sum += __shfl_xor(sum, 32);
      l_r = l_r * corr + sum;
      m_r = mnew;
#pragma unroll
      for (int i = 0; i < 4; ++i)
#pragma unroll
        for (int r = 0; r < 16; ++r) accO[i][r] *= corr;

      u32 cc0[2][4], cc1[2][4];
#pragma unroll
      for (int a = 0; a < 2; ++a)
#pragma unroll
        for (int g = 0; g < 4; ++g) {
          cc0[a][g] = cvtpk(aS[a][g * 4 + 0], aS[a][g * 4 + 1]);
          cc1[a][g] = cvtpk(aS[a][g * 4 + 2], aS[a][g * 4 + 3]);
        }
      bf16x8 pa[4];
#pragma unroll
      for (int ks = 0; ks < 4; ++ks) {
        int a = ks >> 1, g0 = (ks & 1) * 2;
        u32 w0 = cc0[a][g0], w2 = cc0[a][g0 + 1];
        u32 w1 = cc1[a][g0], w3 = cc1[a][g0 + 1];
        plswap(w0, w2);
        plswap(w1, w3);
        u32x4 tv; tv.x = w0; tv.y = w1; tv.z = w2; tv.w = w3;
        pa[ks] = __builtin_bit_cast(bf16x8, tv);
      }
#pragma unroll
      for (int dblk = 0; dblk < 4; ++dblk) {
        int d = dblk * 32 + l31;
#pragma unroll
        for (int ks = 0; ks < 4; ++ks) {
          int c = ks * 2 + hi;
          int cp = c ^ (d & 7);
          bf16x8 vf = *(const bf16x8*)&Vt[cur][d * 64 + cp * 8];
          accO[dblk] = __builtin_amdgcn_mfma_f32_32x32x16_bf16(vf, pa[ks], accO[dblk], 0, 0, 0);
        }
      }
    }

    if (havenext) {
      u32x4 sv = __builtin_bit_cast(u32x4, (lane & 1) ? nv0 : nv1);
      u32x4 rv;
      rv.x = __shfl_xor(sv.x, 1); rv.y = __shfl_xor(sv.y, 1);
      rv.z = __shfl_xor(sv.z, 1); rv.w = __shfl_xor(sv.w, 1);
      bf16x8 recv = __builtin_bit_cast(bf16x8, rv);
      int kvp = lane >> 1;
#pragma unroll
      for (int i = 0; i < 8; ++i) {
        int d = w * 16 + (lane & 1) * 8 + i;
        u16 lo = (lane & 1) ? (u16)recv[i] : (u16)nv0[i];
        u16 hb = (lane & 1) ? (u16)nv1[i] : (u16)recv[i];
        u32 val = (u32)lo | ((u32)hb << 16);
        int cp = (kvp >> 2) ^ (d & 7);
        *(u32*)&Vt[cur ^ 1][d * 64 + cp * 8 + (kvp & 3) * 2] = val;
      }
    }
    __syncthreads();
  }

  {
    float il = 1.0f / l_r;
    size_t rb = ((size_t)b * Ss + qrow) * (size_t)(NHh * HDd) + (size_t)h * HDd;
#pragma unroll
    for (int dblk = 0; dblk < 4; ++dblk)
#pragma unroll
      for (int g = 0; g < 4; ++g) {
        int d0 = dblk * 32 + g * 8 + hi * 4;
        u64 pack = (u64)f2b(accO[dblk][g * 4 + 0] * il) |
                   ((u64)f2b(accO[dblk][g * 4 + 1] * il) << 16) |
                   ((u64)f2b(accO[dblk][g * 4 + 2] * il) << 32) |
                   ((u64)f2b(accO[dblk][g * 4 + 3] * il) << 48);
        *(u64*)&Ctx[rb + d0] = pack;
      }
  }
}

extern "C" void kernel_launch(void* const* d_in, const int* in_sizes, int n_in,
                              void* d_out, int out_size, void* d_ws, size_t ws_size,
                              hipStream_t stream) {
  const float* hidden = (const float*)d_in[0];
  const float* rope = (const float*)d_in[1];
  const float* Wqkv = (const float*)d_in[3];
  const float* bqkv = (const float*)d_in[4];
  const float* Wdense = (const float*)d_in[5];
  float* out = (float*)d_out;

  char* w = (char*)d_ws;
  u16* Xbf = (u16*)w;
  u16* ctx = Xbf;
  w += (size_t)33554432;
  u16* Wq = (u16*)w;
  u16* Wd = Wq;
  w += (size_t)37748736;
  u16* Qb = (u16*)w; w += (size_t)33554432;
  u16* Kb = (u16*)w; w += (size_t)2097152;
  u16* Vb = (u16*)w; w += (size_t)2097152;

  cvt_k<<<(16777216 / 4 + 255) / 256, 256, 0, stream>>>(hidden, Xbf, 16777216);
  cvt_k<<<(18874368 / 4 + 255) / 256, 256, 0, stream>>>(Wqkv, Wq, 18874368);
  // QKV GEMM: 32 x 36 = 1152 blocks
  gemm128<4096, 4608, 4096, 36, 1><<<dim3(1152), 256, 0, stream>>>(
      Xbf, Wq, nullptr, bqkv, Qb, Kb, Vb);
  rope_k<<<(Bb * NHh * Ss * 32 + 255) / 256, 256, 0, stream>>>(Qb, rope, NHh);
  rope_k<<<(Bb * KVHh * Ss * 32 + 255) / 256, 256, 0, stream>>>(Kb, rope, KVHh);
  cvt_k<<<(16777216 / 4 + 255) / 256, 256, 0, stream>>>(Wdense, Wd, 16777216);
  attn_k<<<dim3(8, NHh, Bb), 512, 0, stream>>>(Qb, Kb, Vb, ctx);
  // dense GEMM: 32 x 32 = 1024 blocks
  gemm128<4096, 4096, 4096, 32, 0><<<dim3(1024), 256, 0, stream>>>(
      ctx, Wd, out, nullptr, nullptr, nullptr, nullptr);
}

// Round 6
// 573.643 us; speedup vs baseline: 1.1450x; 1.1450x over previous
//
#include <hip/hip_runtime.h>
#include <hip/hip_bf16.h>
#include <stdint.h>

#define Bb 2
#define Ss 2048
#define Hh 4096
#define NHh 32
#define HDd 128
#define KVHh 2

typedef __attribute__((ext_vector_type(8))) short bf16x8;
typedef __attribute__((ext_vector_type(4))) float f32x4;
typedef __attribute__((ext_vector_type(16))) float f32x16;
typedef __attribute__((ext_vector_type(4))) unsigned int u32x4;
typedef unsigned short u16;
typedef unsigned int u32;
typedef unsigned long long u64;

__device__ __forceinline__ u16 f2b(float f) {
  union { float f; u32 u; } v; v.f = f;
  u32 r = v.u + 0x7fffu + ((v.u >> 16) & 1u);
  return (u16)(r >> 16);
}
__device__ __forceinline__ float b2f(u16 h) {
  union { u32 u; float f; } v; v.u = ((u32)h) << 16;
  return v.f;
}

__device__ __forceinline__ u32 cvtpk(float lo, float hi_) {
  u32 r;
  asm("v_cvt_pk_bf16_f32 %0, %1, %2" : "=v"(r) : "v"(lo), "v"(hi_));
  return r;
}
__device__ __forceinline__ void plswap(u32& x, u32& y) {
  asm volatile("v_permlane32_swap_b32 %0, %1" : "+v"(x), "+v"(y));
}

// async global->LDS, 16B per lane; LDS dest is wave-uniform base + lane*16
__device__ __forceinline__ void gload_lds16(const u16* g, u16* l) {
  __builtin_amdgcn_global_load_lds(
      (const __attribute__((address_space(1))) u32*)(uintptr_t)g,
      (__attribute__((address_space(3))) u32*)(u32)(uintptr_t)l,
      16, 0, 0);
}

// ---------------- f32 -> bf16 convert (vectorized) ----------------
__global__ void cvt_k(const float* __restrict__ in, u16* __restrict__ out, int n) {
  int i = blockIdx.x * blockDim.x + threadIdx.x;
  int idx = i * 4;
  if (idx >= n) return;
  float4 v = *(const float4*)&in[idx];
  u64 pack = (u64)f2b(v.x) | ((u64)f2b(v.y) << 16) |
             ((u64)f2b(v.z) << 32) | ((u64)f2b(v.w) << 48);
  *(u64*)&out[idx] = pack;
}

// ---------------- RoPE in-place on (B, nheads, S, HD) bf16 ----------------
__global__ void rope_k(u16* __restrict__ X, const float* __restrict__ rope, int nheads) {
  int i = blockIdx.x * blockDim.x + threadIdx.x;
  int p = i & 31;
  int s = (i >> 5) & (Ss - 1);
  int bh = i >> 16;
  if (bh >= Bb * nheads) return;
  int b = bh / nheads;
  size_t base = ((size_t)bh * Ss + s) * HDd + p * 2;
  u32 x01 = *(u32*)&X[base];
  float x0 = b2f((u16)(x01 & 0xffff));
  float x1 = b2f((u16)(x01 >> 16));
  float2 rc = *(const float2*)&rope[(((size_t)b * Ss + s) * 32 + p) * 2];
  float o0 = x0 * rc.x - x1 * rc.y;
  float o1 = x1 * rc.x + x0 * rc.y;
  u32 o = (u32)f2b(o0) | ((u32)f2b(o1) << 16);
  *(u32*)&X[base] = o;
}

// ---------------- 128x128 tile GEMM, BK=32, 4 waves, counted-vmcnt dbuf ----------------
// LDS 32KB -> 4 blocks/CU: independent barrier groups hide each other's load latency.
// Swizzle: 16B-chunk c' = c ^ ((row>>1)&3) on BOTH stage-source and ds_read.
// vmcnt(4): only tile t's stage-loads must land; tile t+1's stay in flight.
template <int KK>
__device__ __forceinline__ void stage_tile(const u16* __restrict__ gbase, u16* dst, int tid) {
#pragma unroll
  for (int li = 0; li < 2; ++li) {
    int t16 = li * 256 + tid;
    int rt = t16 >> 2, ct = t16 & 3;
    int cg = ct ^ ((rt >> 1) & 3);
    gload_lds16(gbase + (size_t)rt * KK + cg * 8, dst + t16 * 8);
  }
}

__device__ __forceinline__ bf16x8 frag128(const u16* buf, int row, int lk) {
  int ch = lk ^ ((row >> 1) & 3);
  return *(const bf16x8*)&buf[row * 32 + ch * 8];
}

template <int MM, int NN, int KK, int NBN, int EPI>
__global__ __launch_bounds__(256, 4) void gemm128(
    const u16* __restrict__ A, const u16* __restrict__ Bm,
    float* __restrict__ Cout, const float* __restrict__ bias,
    u16* __restrict__ Qb, u16* __restrict__ Kb, u16* __restrict__ Vb) {
  __shared__ u16 As[2][4096];
  __shared__ u16 Bs[2][4096];
  const int tid = threadIdx.x;
  const int wave = tid >> 6;
  const int lane = tid & 63;
  const int lr = lane & 15;
  const int lk = lane >> 4;
  const int wr = wave >> 1;
  const int wc = wave & 1;
  const int nwg = gridDim.x;
  const int bid = blockIdx.x;
  const int idx = (bid & 7) * (nwg >> 3) + (bid >> 3);
  const int m0 = (idx / NBN) * 128;
  const int n0 = (idx % NBN) * 128;
  const int NT = KK / 32;

  f32x4 acc[4][4];
#pragma unroll
  for (int i = 0; i < 4; ++i)
#pragma unroll
    for (int j = 0; j < 4; ++j) acc[i][j] = (f32x4){0.f, 0.f, 0.f, 0.f};

  const u16* Ab = A + (size_t)m0 * KK;
  const u16* Bb_ = Bm + (size_t)n0 * KK;

  stage_tile<KK>(Ab, &As[0][0], tid);
  stage_tile<KK>(Bb_, &Bs[0][0], tid);
  asm volatile("s_waitcnt vmcnt(0)");
  __syncthreads();

  int cur = 0;
  for (int t = 0; t < NT; ++t) {
    if (t + 1 < NT) {
      stage_tile<KK>(Ab + (t + 1) * 32, &As[cur ^ 1][0], tid);
      stage_tile<KK>(Bb_ + (t + 1) * 32, &Bs[cur ^ 1][0], tid);
      asm volatile("s_waitcnt vmcnt(4)");
    } else {
      asm volatile("s_waitcnt vmcnt(0)");
    }
    __builtin_amdgcn_s_barrier();
    __builtin_amdgcn_sched_barrier(0);

    bf16x8 af[4], bf[4];
#pragma unroll
    for (int mi = 0; mi < 4; ++mi)
      af[mi] = frag128(&As[cur][0], wr * 64 + mi * 16 + lr, lk);
#pragma unroll
    for (int ni = 0; ni < 4; ++ni)
      bf[ni] = frag128(&Bs[cur][0], wc * 64 + ni * 16 + lr, lk);
    asm volatile("s_waitcnt lgkmcnt(0)");
    __builtin_amdgcn_sched_barrier(0);
    __builtin_amdgcn_s_setprio(1);
#pragma unroll
    for (int mi = 0; mi < 4; ++mi)
#pragma unroll
      for (int ni = 0; ni < 4; ++ni)
        acc[mi][ni] = __builtin_amdgcn_mfma_f32_16x16x32_bf16(af[mi], bf[ni], acc[mi][ni], 0, 0, 0);
    __builtin_amdgcn_s_setprio(0);
    __builtin_amdgcn_s_barrier();
    cur ^= 1;
  }

  if constexpr (EPI == 0) {
#pragma unroll
    for (int mi = 0; mi < 4; ++mi)
#pragma unroll
      for (int ni = 0; ni < 4; ++ni) {
        int col = n0 + wc * 64 + ni * 16 + lr;
        int rowb = m0 + wr * 64 + mi * 16 + lk * 4;
#pragma unroll
        for (int j = 0; j < 4; ++j)
          Cout[(size_t)(rowb + j) * NN + col] = acc[mi][ni][j];
      }
  } else {
#pragma unroll
    for (int ni = 0; ni < 4; ++ni) {
      int n = n0 + wc * 64 + ni * 16 + lr;
      float bv = bias[n];
#pragma unroll
      for (int mi = 0; mi < 4; ++mi) {
        int mb = m0 + wr * 64 + mi * 16 + lk * 4;
#pragma unroll
        for (int j = 0; j < 4; ++j) {
          int m = mb + j;
          int bb = m >> 11;
          int ss = m & 2047;
          u16 hv = f2b(acc[mi][ni][j] + bv);
          if (n < 4096) {
            Qb[(((size_t)bb * NHh + (n >> 7)) * Ss + ss) * HDd + (n & 127)] = hv;
          } else if (n < 4352) {
            int idx2 = n - 4096;
            Kb[(((size_t)bb * KVHh + (idx2 >> 7)) * Ss + ss) * HDd + (idx2 & 127)] = hv;
          } else {
            int idx2 = n - 4352;
            Vb[(((size_t)bb * KVHh + (idx2 >> 7)) * Ss + ss) * HDd + (idx2 & 127)] = hv;
          }
        }
      }
    }
  }
}

// ---------------- causal GQA flash attention, 8-wave 32x32 swapped-QK^T ----------------
// grid (4, NH, B): block x processes q-tile PAIR {7-x, x} -> 36 KV-iters for EVERY
// block (4(7-x)+4 + 4x+4 = 36): perfect causal load balance, 256 blocks = 1/CU.
__global__ __launch_bounds__(512, 2) void attn_k(
    const u16* __restrict__ Qb, const u16* __restrict__ Kb,
    const u16* __restrict__ Vb, u16* __restrict__ Ctx) {
  __shared__ u16 Kt[2][64 * 128];
  __shared__ u16 Vt[2][128 * 64];
  const int tid = threadIdx.x;
  const int w = tid >> 6;
  const int lane = tid & 63;
  const int l31 = lane & 31;
  const int hi = lane >> 5;
  const int h = blockIdx.y, b = blockIdx.z;
  const int hkv = h >> 4;
  const u16* Qp = Qb + ((size_t)(b * NHh + h)) * Ss * HDd;
  const u16* Kp = Kb + ((size_t)(b * KVHh + hkv)) * Ss * HDd;
  const u16* Vp = Vb + ((size_t)(b * KVHh + hkv)) * Ss * HDd;

  const float scale = 0.08838834764831845f;
  const float L2E = 1.4426950408889634f;

  for (int hp = 0; hp < 2; ++hp) {
    const int qt = hp == 0 ? (7 - (int)blockIdx.x) : (int)blockIdx.x;
    const int qs = qt * 256;
    const int qw = qs + w * 32;
    const int qrow = qw + l31;
    const int nt = qs / 64 + 4;

    bf16x8 qf[8];
#pragma unroll
    for (int ds = 0; ds < 8; ++ds)
      qf[ds] = *(const bf16x8*)&Qp[(size_t)qrow * HDd + ds * 16 + hi * 8];

    f32x16 accO[4];
#pragma unroll
    for (int i = 0; i < 4; ++i)
#pragma unroll
      for (int r = 0; r < 16; ++r) accO[i][r] = 0.f;
    float m_r = -3.0e38f, l_r = 0.f;

    // ---- prologue: stage tile 0 into buf 0 ----
    {
#pragma unroll
      for (int i = 0; i < 2; ++i) {
        int slot = w * 2 + i;
        int r = slot * 4 + (lane >> 4);
        int p = lane & 15;
        int gc = (p & 8) | ((p ^ r) & 7);
        gload_lds16(Kp + (size_t)r * HDd + gc * 8, &Kt[0][slot * 512]);
      }
      bf16x8 v0 = *(const bf16x8*)&Vp[(size_t)lane * HDd + w * 16];
      bf16x8 v1 = *(const bf16x8*)&Vp[(size_t)lane * HDd + w * 16 + 8];
      u32x4 sv = __builtin_bit_cast(u32x4, (lane & 1) ? v0 : v1);
      u32x4 rv;
      rv.x = __shfl_xor(sv.x, 1); rv.y = __shfl_xor(sv.y, 1);
      rv.z = __shfl_xor(sv.z, 1); rv.w = __shfl_xor(sv.w, 1);
      bf16x8 recv = __builtin_bit_cast(bf16x8, rv);
      int kvp = lane >> 1;
#pragma unroll
      for (int i = 0; i < 8; ++i) {
        int d = w * 16 + (lane & 1) * 8 + i;
        u16 lo = (lane & 1) ? (u16)recv[i] : (u16)v0[i];
        u16 hb = (lane & 1) ? (u16)v1[i] : (u16)recv[i];
        u32 val = (u32)lo | ((u32)hb << 16);
        int cp = (kvp >> 2) ^ (d & 7);
        *(u32*)&Vt[0][d * 64 + cp * 8 + (kvp & 3) * 2] = val;
      }
    }
    __syncthreads();

    for (int t = 0; t < nt; ++t) {
      const int j0 = t * 64;
      const int cur = t & 1;
      const bool havenext = (t + 1 < nt);
      bf16x8 nv0, nv1;
      if (havenext) {
        const int j1 = j0 + 64;
#pragma unroll
        for (int i = 0; i < 2; ++i) {
          int slot = w * 2 + i;
          int r = slot * 4 + (lane >> 4);
          int p = lane & 15;
          int gc = (p & 8) | ((p ^ r) & 7);
          gload_lds16(Kp + (size_t)(j1 + r) * HDd + gc * 8, &Kt[cur ^ 1][slot * 512]);
        }
        nv0 = *(const bf16x8*)&Vp[(size_t)(j1 + lane) * HDd + w * 16];
        nv1 = *(const bf16x8*)&Vp[(size_t)(j1 + lane) * HDd + w * 16 + 8];
      }

      if (j0 <= qw + 31) {
        f32x16 aS[2];
#pragma unroll
        for (int a = 0; a < 2; ++a)
#pragma unroll
          for (int r = 0; r < 16; ++r) aS[a][r] = 0.f;
#pragma unroll
        for (int kvb = 0; kvb < 2; ++kvb) {
          int r = kvb * 32 + l31;
#pragma unroll
          for (int ds = 0; ds < 8; ++ds) {
            int c = ds * 2 + hi;
            int cp = (c & 8) | ((c ^ r) & 7);
            bf16x8 kf = *(const bf16x8*)&Kt[cur][r * 128 + cp * 8];
            aS[kvb] = __builtin_amdgcn_mfma_f32_32x32x16_bf16(kf, qf[ds], aS[kvb], 0, 0, 0);
          }
        }
        const bool needmask = (j0 + 63 > qw);
        float mx = -3.0e38f;
#pragma unroll
        for (int a = 0; a < 2; ++a)
#pragma unroll
          for (int r = 0; r < 16; ++r) {
            float s = aS[a][r] * scale;
            if (needmask) {
              int kv = j0 + a * 32 + (r & 3) + 8 * (r >> 2) + 4 * hi;
              s = (kv > qrow) ? -3.0e38f : s;
            }
            aS[a][r] = s;
            mx = fmaxf(mx, s);
          }
        mx = fmaxf(mx, __shfl_xor(mx, 32));
        float mnew = fmaxf(m_r, mx);
        float corr = __builtin_amdgcn_exp2f((m_r - mnew) * L2E);
        float sum = 0.f;
#pragma unroll
        for (int a = 0; a < 2; ++a)
#pragma unroll
          for (int r = 0; r < 16; ++r) {
            float pe = __builtin_amdgcn_exp2f((aS[a][r] - mnew) * L2E);
            aS[a][r] = pe;
            sum += pe;
          }
        sum += __shfl_xor(sum, 32);
        l_r = l_r * corr + sum;
        m_r = mnew;
#pragma unroll
        for (int i = 0; i < 4; ++i)
#pragma unroll
          for (int r = 0; r < 16; ++r) accO[i][r] *= corr;

        u32 cc0[2][4], cc1[2][4];
#pragma unroll
        for (int a = 0; a < 2; ++a)
#pragma unroll
          for (int g = 0; g < 4; ++g) {
            cc0[a][g] = cvtpk(aS[a][g * 4 + 0], aS[a][g * 4 + 1]);
            cc1[a][g] = cvtpk(aS[a][g * 4 + 2], aS[a][g * 4 + 3]);
          }
        bf16x8 pa[4];
#pragma unroll
        for (int ks = 0; ks < 4; ++ks) {
          int a = ks >> 1, g0 = (ks & 1) * 2;
          u32 w0 = cc0[a][g0], w2 = cc0[a][g0 + 1];
          u32 w1 = cc1[a][g0], w3 = cc1[a][g0 + 1];
          plswap(w0, w2);
          plswap(w1, w3);
          u32x4 tv; tv.x = w0; tv.y = w1; tv.z = w2; tv.w = w3;
          pa[ks] = __builtin_bit_cast(bf16x8, tv);
        }
#pragma unroll
        for (int dblk = 0; dblk < 4; ++dblk) {
          int d = dblk * 32 + l31;
#pragma unroll
          for (int ks = 0; ks < 4; ++ks) {
            int c = ks * 2 + hi;
            int cp = c ^ (d & 7);
            bf16x8 vf = *(const bf16x8*)&Vt[cur][d * 64 + cp * 8];
            accO[dblk] = __builtin_amdgcn_mfma_f32_32x32x16_bf16(vf, pa[ks], accO[dblk], 0, 0, 0);
          }
        }
      }

      if (havenext) {
        u32x4 sv = __builtin_bit_cast(u32x4, (lane & 1) ? nv0 : nv1);
        u32x4 rv;
        rv.x = __shfl_xor(sv.x, 1); rv.y = __shfl_xor(sv.y, 1);
        rv.z = __shfl_xor(sv.z, 1); rv.w = __shfl_xor(sv.w, 1);
        bf16x8 recv = __builtin_bit_cast(bf16x8, rv);
        int kvp = lane >> 1;
#pragma unroll
        for (int i = 0; i < 8; ++i) {
          int d = w * 16 + (lane & 1) * 8 + i;
          u16 lo = (lane & 1) ? (u16)recv[i] : (u16)nv0[i];
          u16 hb = (lane & 1) ? (u16)nv1[i] : (u16)recv[i];
          u32 val = (u32)lo | ((u32)hb << 16);
          int cp = (kvp >> 2) ^ (d & 7);
          *(u32*)&Vt[cur ^ 1][d * 64 + cp * 8 + (kvp & 3) * 2] = val;
        }
      }
      __syncthreads();
    }

    // ---- epilogue: O^T/l -> ctx (b, q, h*128+d) bf16 ----
    {
      float il = 1.0f / l_r;
      size_t rb = ((size_t)b * Ss + qrow) * (size_t)(NHh * HDd) + (size_t)h * HDd;
#pragma unroll
      for (int dblk = 0; dblk < 4; ++dblk)
#pragma unroll
        for (int g = 0; g < 4; ++g) {
          int d0 = dblk * 32 + g * 8 + hi * 4;
          u64 pack = (u64)f2b(accO[dblk][g * 4 + 0] * il) |
                     ((u64)f2b(accO[dblk][g * 4 + 1] * il) << 16) |
                     ((u64)f2b(accO[dblk][g * 4 + 2] * il) << 32) |
                     ((u64)f2b(accO[dblk][g * 4 + 3] * il) << 48);
          *(u64*)&Ctx[rb + d0] = pack;
        }
    }
    __syncthreads();
  }
}

extern "C" void kernel_launch(void* const* d_in, const int* in_sizes, int n_in,
                              void* d_out, int out_size, void* d_ws, size_t ws_size,
                              hipStream_t stream) {
  const float* hidden = (const float*)d_in[0];
  const float* rope = (const float*)d_in[1];
  const float* Wqkv = (const float*)d_in[3];
  const float* bqkv = (const float*)d_in[4];
  const float* Wdense = (const float*)d_in[5];
  float* out = (float*)d_out;

  char* w = (char*)d_ws;
  u16* Xbf = (u16*)w;
  u16* ctx = Xbf;
  w += (size_t)33554432;
  u16* Wq = (u16*)w;
  u16* Wd = Wq;
  w += (size_t)37748736;
  u16* Qb = (u16*)w; w += (size_t)33554432;
  u16* Kb = (u16*)w; w += (size_t)2097152;
  u16* Vb = (u16*)w; w += (size_t)2097152;

  cvt_k<<<(16777216 / 4 + 255) / 256, 256, 0, stream>>>(hidden, Xbf, 16777216);
  cvt_k<<<(18874368 / 4 + 255) / 256, 256, 0, stream>>>(Wqkv, Wq, 18874368);
  // QKV GEMM: 32 x 36 = 1152 blocks
  gemm128<4096, 4608, 4096, 36, 1><<<dim3(1152), 256, 0, stream>>>(
      Xbf, Wq, nullptr, bqkv, Qb, Kb, Vb);
  rope_k<<<(Bb * NHh * Ss * 32 + 255) / 256, 256, 0, stream>>>(Qb, rope, NHh);
  rope_k<<<(Bb * KVHh * Ss * 32 + 255) / 256, 256, 0, stream>>>(Kb, rope, KVHh);
  cvt_k<<<(16777216 / 4 + 255) / 256, 256, 0, stream>>>(Wdense, Wd, 16777216);
  // balanced causal pairing: grid (4, NH, B)
  attn_k<<<dim3(4, NHh, Bb), 512, 0, stream>>>(Qb, Kb, Vb, ctx);
  // dense GEMM: 32 x 32 = 1024 blocks
  gemm128<4096, 4096, 4096, 32, 0><<<dim3(1024), 256, 0, stream>>>(
      ctx, Wd, out, nullptr, nullptr, nullptr, nullptr);
}

// Round 7
// 525.520 us; speedup vs baseline: 1.2498x; 1.0916x over previous
//
#include <hip/hip_runtime.h>
#include <hip/hip_bf16.h>
#include <stdint.h>

#define Bb 2
#define Ss 2048
#define Hh 4096
#define NHh 32
#define HDd 128
#define KVHh 2

typedef __attribute__((ext_vector_type(8))) short bf16x8;
typedef __attribute__((ext_vector_type(4))) float f32x4;
typedef __attribute__((ext_vector_type(16))) float f32x16;
typedef __attribute__((ext_vector_type(4))) unsigned int u32x4;
typedef unsigned short u16;
typedef unsigned int u32;
typedef unsigned long long u64;

__device__ __forceinline__ u16 f2b(float f) {
  union { float f; u32 u; } v; v.f = f;
  u32 r = v.u + 0x7fffu + ((v.u >> 16) & 1u);
  return (u16)(r >> 16);
}
__device__ __forceinline__ float b2f(u16 h) {
  union { u32 u; float f; } v; v.u = ((u32)h) << 16;
  return v.f;
}

__device__ __forceinline__ u32 cvtpk(float lo, float hi_) {
  u32 r;
  asm("v_cvt_pk_bf16_f32 %0, %1, %2" : "=v"(r) : "v"(lo), "v"(hi_));
  return r;
}
__device__ __forceinline__ void plswap(u32& x, u32& y) {
  asm volatile("v_permlane32_swap_b32 %0, %1" : "+v"(x), "+v"(y));
}

// async global->LDS, 16B per lane; LDS dest is wave-uniform base + lane*16
__device__ __forceinline__ void gload_lds16(const u16* g, u16* l) {
  __builtin_amdgcn_global_load_lds(
      (const __attribute__((address_space(1))) u32*)(uintptr_t)g,
      (__attribute__((address_space(3))) u32*)(u32)(uintptr_t)l,
      16, 0, 0);
}

// ---------------- f32 -> bf16 convert (vectorized) ----------------
__global__ void cvt_k(const float* __restrict__ in, u16* __restrict__ out, int n) {
  int i = blockIdx.x * blockDim.x + threadIdx.x;
  int idx = i * 4;
  if (idx >= n) return;
  float4 v = *(const float4*)&in[idx];
  u64 pack = (u64)f2b(v.x) | ((u64)f2b(v.y) << 16) |
             ((u64)f2b(v.z) << 32) | ((u64)f2b(v.w) << 48);
  *(u64*)&out[idx] = pack;
}

// ---------------- RoPE in-place on (B, nheads, S, HD) bf16 ----------------
__global__ void rope_k(u16* __restrict__ X, const float* __restrict__ rope, int nheads) {
  int i = blockIdx.x * blockDim.x + threadIdx.x;
  int p = i & 31;
  int s = (i >> 5) & (Ss - 1);
  int bh = i >> 16;
  if (bh >= Bb * nheads) return;
  int b = bh / nheads;
  size_t base = ((size_t)bh * Ss + s) * HDd + p * 2;
  u32 x01 = *(u32*)&X[base];
  float x0 = b2f((u16)(x01 & 0xffff));
  float x1 = b2f((u16)(x01 >> 16));
  float2 rc = *(const float2*)&rope[(((size_t)b * Ss + s) * 32 + p) * 2];
  float o0 = x0 * rc.x - x1 * rc.y;
  float o1 = x1 * rc.x + x0 * rc.y;
  u32 o = (u32)f2b(o0) | ((u32)f2b(o1) << 16);
  *(u32*)&X[base] = o;
}

// ---------------- 128x128 tile GEMM, BK=32, 4 waves, counted-vmcnt dbuf ----------------
// LDS 32KB -> 4-5 blocks/CU: independent barrier groups hide each other's latency.
// Swizzle: 16B-chunk c' = c ^ ((row>>1)&3) on BOTH stage-source and ds_read.
// vmcnt(4): only tile t's stage-loads must land; tile t+1's stay in flight.
// L2-aware block->tile map: each XCD owns a SQUARE-ISH region (16 rows x COLG cols)
// -> concurrent working set per XCD per K-step = (16+COLG)*8KB, minimizing L2-miss
// traffic (the (R+C) term); row-stripe regions were 636 MB FETCH/dispatch (R6).
template <int KK>
__device__ __forceinline__ void stage_tile(const u16* __restrict__ gbase, u16* dst, int tid) {
#pragma unroll
  for (int li = 0; li < 2; ++li) {
    int t16 = li * 256 + tid;
    int rt = t16 >> 2, ct = t16 & 3;
    int cg = ct ^ ((rt >> 1) & 3);
    gload_lds16(gbase + (size_t)rt * KK + cg * 8, dst + t16 * 8);
  }
}

__device__ __forceinline__ bf16x8 frag128(const u16* buf, int row, int lk) {
  int ch = lk ^ ((row >> 1) & 3);
  return *(const bf16x8*)&buf[row * 32 + ch * 8];
}

template <int MM, int NN, int KK, int COLG, int EPI>
__global__ __launch_bounds__(256, 4) void gemm128(
    const u16* __restrict__ A, const u16* __restrict__ Bm,
    float* __restrict__ Cout, const float* __restrict__ bias,
    u16* __restrict__ Qb, u16* __restrict__ Kb, u16* __restrict__ Vb) {
  __shared__ u16 As[2][4096];
  __shared__ u16 Bs[2][4096];
  const int tid = threadIdx.x;
  const int wave = tid >> 6;
  const int lane = tid & 63;
  const int lr = lane & 15;
  const int lk = lane >> 4;
  const int wr = wave >> 1;
  const int wc = wave & 1;
  // XCD-region map: xcd -> (rowgrp 0..1, colgrp 0..3); region 16 x COLG tiles, row-major
  const int bid = blockIdx.x;
  const int xcd = bid & 7;
  const int local = bid >> 3;
  const int rlr = local / COLG;
  const int rlc = local - rlr * COLG;
  const int m0 = ((xcd >> 2) * 16 + rlr) * 128;
  const int n0 = ((xcd & 3) * COLG + rlc) * 128;
  const int NT = KK / 32;

  f32x4 acc[4][4];
#pragma unroll
  for (int i = 0; i < 4; ++i)
#pragma unroll
    for (int j = 0; j < 4; ++j) acc[i][j] = (f32x4){0.f, 0.f, 0.f, 0.f};

  const u16* Ab = A + (size_t)m0 * KK;
  const u16* Bb_ = Bm + (size_t)n0 * KK;

  stage_tile<KK>(Ab, &As[0][0], tid);
  stage_tile<KK>(Bb_, &Bs[0][0], tid);
  asm volatile("s_waitcnt vmcnt(0)");
  __syncthreads();

  int cur = 0;
  for (int t = 0; t < NT; ++t) {
    if (t + 1 < NT) {
      stage_tile<KK>(Ab + (t + 1) * 32, &As[cur ^ 1][0], tid);
      stage_tile<KK>(Bb_ + (t + 1) * 32, &Bs[cur ^ 1][0], tid);
      asm volatile("s_waitcnt vmcnt(4)");
    } else {
      asm volatile("s_waitcnt vmcnt(0)");
    }
    __builtin_amdgcn_s_barrier();
    __builtin_amdgcn_sched_barrier(0);

    bf16x8 af[4], bf[4];
#pragma unroll
    for (int mi = 0; mi < 4; ++mi)
      af[mi] = frag128(&As[cur][0], wr * 64 + mi * 16 + lr, lk);
#pragma unroll
    for (int ni = 0; ni < 4; ++ni)
      bf[ni] = frag128(&Bs[cur][0], wc * 64 + ni * 16 + lr, lk);
    asm volatile("s_waitcnt lgkmcnt(0)");
    __builtin_amdgcn_sched_barrier(0);
    __builtin_amdgcn_s_setprio(1);
#pragma unroll
    for (int mi = 0; mi < 4; ++mi)
#pragma unroll
      for (int ni = 0; ni < 4; ++ni)
        acc[mi][ni] = __builtin_amdgcn_mfma_f32_16x16x32_bf16(af[mi], bf[ni], acc[mi][ni], 0, 0, 0);
    __builtin_amdgcn_s_setprio(0);
    __builtin_amdgcn_s_barrier();
    cur ^= 1;
  }

  if constexpr (EPI == 0) {
#pragma unroll
    for (int mi = 0; mi < 4; ++mi)
#pragma unroll
      for (int ni = 0; ni < 4; ++ni) {
        int col = n0 + wc * 64 + ni * 16 + lr;
        int rowb = m0 + wr * 64 + mi * 16 + lk * 4;
#pragma unroll
        for (int j = 0; j < 4; ++j)
          Cout[(size_t)(rowb + j) * NN + col] = acc[mi][ni][j];
      }
  } else {
#pragma unroll
    for (int ni = 0; ni < 4; ++ni) {
      int n = n0 + wc * 64 + ni * 16 + lr;
      float bv = bias[n];
#pragma unroll
      for (int mi = 0; mi < 4; ++mi) {
        int mb = m0 + wr * 64 + mi * 16 + lk * 4;
#pragma unroll
        for (int j = 0; j < 4; ++j) {
          int m = mb + j;
          int bb = m >> 11;
          int ss = m & 2047;
          u16 hv = f2b(acc[mi][ni][j] + bv);
          if (n < 4096) {
            Qb[(((size_t)bb * NHh + (n >> 7)) * Ss + ss) * HDd + (n & 127)] = hv;
          } else if (n < 4352) {
            int idx2 = n - 4096;
            Kb[(((size_t)bb * KVHh + (idx2 >> 7)) * Ss + ss) * HDd + (idx2 & 127)] = hv;
          } else {
            int idx2 = n - 4352;
            Vb[(((size_t)bb * KVHh + (idx2 >> 7)) * Ss + ss) * HDd + (idx2 & 127)] = hv;
          }
        }
      }
    }
  }
}

// ---------------- causal GQA flash attention, 8-wave 32x32 swapped-QK^T ----------------
// grid (4, NH, B): block x processes q-tile PAIR {7-x, x} -> 36 KV-iters for EVERY
// block: perfect causal load balance, 256 blocks = 1/CU.
__global__ __launch_bounds__(512, 2) void attn_k(
    const u16* __restrict__ Qb, const u16* __restrict__ Kb,
    const u16* __restrict__ Vb, u16* __restrict__ Ctx) {
  __shared__ u16 Kt[2][64 * 128];
  __shared__ u16 Vt[2][128 * 64];
  const int tid = threadIdx.x;
  const int w = tid >> 6;
  const int lane = tid & 63;
  const int l31 = lane & 31;
  const int hi = lane >> 5;
  const int h = blockIdx.y, b = blockIdx.z;
  const int hkv = h >> 4;
  const u16* Qp = Qb + ((size_t)(b * NHh + h)) * Ss * HDd;
  const u16* Kp = Kb + ((size_t)(b * KVHh + hkv)) * Ss * HDd;
  const u16* Vp = Vb + ((size_t)(b * KVHh + hkv)) * Ss * HDd;

  const float scale = 0.08838834764831845f;
  const float L2E = 1.4426950408889634f;

  for (int hp = 0; hp < 2; ++hp) {
    const int qt = hp == 0 ? (7 - (int)blockIdx.x) : (int)blockIdx.x;
    const int qs = qt * 256;
    const int qw = qs + w * 32;
    const int qrow = qw + l31;
    const int nt = qs / 64 + 4;

    bf16x8 qf[8];
#pragma unroll
    for (int ds = 0; ds < 8; ++ds)
      qf[ds] = *(const bf16x8*)&Qp[(size_t)qrow * HDd + ds * 16 + hi * 8];

    f32x16 accO[4];
#pragma unroll
    for (int i = 0; i < 4; ++i)
#pragma unroll
      for (int r = 0; r < 16; ++r) accO[i][r] = 0.f;
    float m_r = -3.0e38f, l_r = 0.f;

    {
#pragma unroll
      for (int i = 0; i < 2; ++i) {
        int slot = w * 2 + i;
        int r = slot * 4 + (lane >> 4);
        int p = lane & 15;
        int gc = (p & 8) | ((p ^ r) & 7);
        gload_lds16(Kp + (size_t)r * HDd + gc * 8, &Kt[0][slot * 512]);
      }
      bf16x8 v0 = *(const bf16x8*)&Vp[(size_t)lane * HDd + w * 16];
      bf16x8 v1 = *(const bf16x8*)&Vp[(size_t)lane * HDd + w * 16 + 8];
      u32x4 sv = __builtin_bit_cast(u32x4, (lane & 1) ? v0 : v1);
      u32x4 rv;
      rv.x = __shfl_xor(sv.x, 1); rv.y = __shfl_xor(sv.y, 1);
      rv.z = __shfl_xor(sv.z, 1); rv.w = __shfl_xor(sv.w, 1);
      bf16x8 recv = __builtin_bit_cast(bf16x8, rv);
      int kvp = lane >> 1;
#pragma unroll
      for (int i = 0; i < 8; ++i) {
        int d = w * 16 + (lane & 1) * 8 + i;
        u16 lo = (lane & 1) ? (u16)recv[i] : (u16)v0[i];
        u16 hb = (lane & 1) ? (u16)v1[i] : (u16)recv[i];
        u32 val = (u32)lo | ((u32)hb << 16);
        int cp = (kvp >> 2) ^ (d & 7);
        *(u32*)&Vt[0][d * 64 + cp * 8 + (kvp & 3) * 2] = val;
      }
    }
    __syncthreads();

    for (int t = 0; t < nt; ++t) {
      const int j0 = t * 64;
      const int cur = t & 1;
      const bool havenext = (t + 1 < nt);
      bf16x8 nv0, nv1;
      if (havenext) {
        const int j1 = j0 + 64;
#pragma unroll
        for (int i = 0; i < 2; ++i) {
          int slot = w * 2 + i;
          int r = slot * 4 + (lane >> 4);
          int p = lane & 15;
          int gc = (p & 8) | ((p ^ r) & 7);
          gload_lds16(Kp + (size_t)(j1 + r) * HDd + gc * 8, &Kt[cur ^ 1][slot * 512]);
        }
        nv0 = *(const bf16x8*)&Vp[(size_t)(j1 + lane) * HDd + w * 16];
        nv1 = *(const bf16x8*)&Vp[(size_t)(j1 + lane) * HDd + w * 16 + 8];
      }

      if (j0 <= qw + 31) {
        f32x16 aS[2];
#pragma unroll
        for (int a = 0; a < 2; ++a)
#pragma unroll
          for (int r = 0; r < 16; ++r) aS[a][r] = 0.f;
#pragma unroll
        for (int kvb = 0; kvb < 2; ++kvb) {
          int r = kvb * 32 + l31;
#pragma unroll
          for (int ds = 0; ds < 8; ++ds) {
            int c = ds * 2 + hi;
            int cp = (c & 8) | ((c ^ r) & 7);
            bf16x8 kf = *(const bf16x8*)&Kt[cur][r * 128 + cp * 8];
            aS[kvb] = __builtin_amdgcn_mfma_f32_32x32x16_bf16(kf, qf[ds], aS[kvb], 0, 0, 0);
          }
        }
        const bool needmask = (j0 + 63 > qw);
        float mx = -3.0e38f;
#pragma unroll
        for (int a = 0; a < 2; ++a)
#pragma unroll
          for (int r = 0; r < 16; ++r) {
            float s = aS[a][r] * scale;
            if (needmask) {
              int kv = j0 + a * 32 + (r & 3) + 8 * (r >> 2) + 4 * hi;
              s = (kv > qrow) ? -3.0e38f : s;
            }
            aS[a][r] = s;
            mx = fmaxf(mx, s);
          }
        mx = fmaxf(mx, __shfl_xor(mx, 32));
        float mnew = fmaxf(m_r, mx);
        float corr = __builtin_amdgcn_exp2f((m_r - mnew) * L2E);
        float sum = 0.f;
#pragma unroll
        for (int a = 0; a < 2; ++a)
#pragma unroll
          for (int r = 0; r < 16; ++r) {
            float pe = __builtin_amdgcn_exp2f((aS[a][r] - mnew) * L2E);
            aS[a][r] = pe;
            sum += pe;
          }
        sum += __shfl_xor(sum, 32);
        l_r = l_r * corr + sum;
        m_r = mnew;
#pragma unroll
        for (int i = 0; i < 4; ++i)
#pragma unroll
          for (int r = 0; r < 16; ++r) accO[i][r] *= corr;

        u32 cc0[2][4], cc1[2][4];
#pragma unroll
        for (int a = 0; a < 2; ++a)
#pragma unroll
          for (int g = 0; g < 4; ++g) {
            cc0[a][g] = cvtpk(aS[a][g * 4 + 0], aS[a][g * 4 + 1]);
            cc1[a][g] = cvtpk(aS[a][g * 4 + 2], aS[a][g * 4 + 3]);
          }
        bf16x8 pa[4];
#pragma unroll
        for (int ks = 0; ks < 4; ++ks) {
          int a = ks >> 1, g0 = (ks & 1) * 2;
          u32 w0 = cc0[a][g0], w2 = cc0[a][g0 + 1];
          u32 w1 = cc1[a][g0], w3 = cc1[a][g0 + 1];
          plswap(w0, w2);
          plswap(w1, w3);
          u32x4 tv; tv.x = w0; tv.y = w1; tv.z = w2; tv.w = w3;
          pa[ks] = __builtin_bit_cast(bf16x8, tv);
        }
#pragma unroll
        for (int dblk = 0; dblk < 4; ++dblk) {
          int d = dblk * 32 + l31;
#pragma unroll
          for (int ks = 0; ks < 4; ++ks) {
            int c = ks * 2 + hi;
            int cp = c ^ (d & 7);
            bf16x8 vf = *(const bf16x8*)&Vt[cur][d * 64 + cp * 8];
            accO[dblk] = __builtin_amdgcn_mfma_f32_32x32x16_bf16(vf, pa[ks], accO[dblk], 0, 0, 0);
          }
        }
      }

      if (havenext) {
        u32x4 sv = __builtin_bit_cast(u32x4, (lane & 1) ? nv0 : nv1);
        u32x4 rv;
        rv.x = __shfl_xor(sv.x, 1); rv.y = __shfl_xor(sv.y, 1);
        rv.z = __shfl_xor(sv.z, 1); rv.w = __shfl_xor(sv.w, 1);
        bf16x8 recv = __builtin_bit_cast(bf16x8, rv);
        int kvp = lane >> 1;
#pragma unroll
        for (int i = 0; i < 8; ++i) {
          int d = w * 16 + (lane & 1) * 8 + i;
          u16 lo = (lane & 1) ? (u16)recv[i] : (u16)nv0[i];
          u16 hb = (lane & 1) ? (u16)nv1[i] : (u16)recv[i];
          u32 val = (u32)lo | ((u32)hb << 16);
          int cp = (kvp >> 2) ^ (d & 7);
          *(u32*)&Vt[cur ^ 1][d * 64 + cp * 8 + (kvp & 3) * 2] = val;
        }
      }
      __syncthreads();
    }

    {
      float il = 1.0f / l_r;
      size_t rb = ((size_t)b * Ss + qrow) * (size_t)(NHh * HDd) + (size_t)h * HDd;
#pragma unroll
      for (int dblk = 0; dblk < 4; ++dblk)
#pragma unroll
        for (int g = 0; g < 4; ++g) {
          int d0 = dblk * 32 + g * 8 + hi * 4;
          u64 pack = (u64)f2b(accO[dblk][g * 4 + 0] * il) |
                     ((u64)f2b(accO[dblk][g * 4 + 1] * il) << 16) |
                     ((u64)f2b(accO[dblk][g * 4 + 2] * il) << 32) |
                     ((u64)f2b(accO[dblk][g * 4 + 3] * il) << 48);
          *(u64*)&Ctx[rb + d0] = pack;
        }
    }
    __syncthreads();
  }
}

extern "C" void kernel_launch(void* const* d_in, const int* in_sizes, int n_in,
                              void* d_out, int out_size, void* d_ws, size_t ws_size,
                              hipStream_t stream) {
  const float* hidden = (const float*)d_in[0];
  const float* rope = (const float*)d_in[1];
  const float* Wqkv = (const float*)d_in[3];
  const float* bqkv = (const float*)d_in[4];
  const float* Wdense = (const float*)d_in[5];
  float* out = (float*)d_out;

  char* w = (char*)d_ws;
  u16* Xbf = (u16*)w;
  u16* ctx = Xbf;
  w += (size_t)33554432;
  u16* Wq = (u16*)w;
  u16* Wd = Wq;
  w += (size_t)37748736;
  u16* Qb = (u16*)w; w += (size_t)33554432;
  u16* Kb = (u16*)w; w += (size_t)2097152;
  u16* Vb = (u16*)w; w += (size_t)2097152;

  cvt_k<<<(16777216 / 4 + 255) / 256, 256, 0, stream>>>(hidden, Xbf, 16777216);
  cvt_k<<<(18874368 / 4 + 255) / 256, 256, 0, stream>>>(Wqkv, Wq, 18874368);
  // QKV GEMM: 32 x 36 tiles; regions 16 x 9 per XCD
  gemm128<4096, 4608, 4096, 9, 1><<<dim3(1152), 256, 0, stream>>>(
      Xbf, Wq, nullptr, bqkv, Qb, Kb, Vb);
  rope_k<<<(Bb * NHh * Ss * 32 + 255) / 256, 256, 0, stream>>>(Qb, rope, NHh);
  rope_k<<<(Bb * KVHh * Ss * 32 + 255) / 256, 256, 0, stream>>>(Kb, rope, KVHh);
  cvt_k<<<(16777216 / 4 + 255) / 256, 256, 0, stream>>>(Wdense, Wd, 16777216);
  // balanced causal pairing: grid (4, NH, B)
  attn_k<<<dim3(4, NHh, Bb), 512, 0, stream>>>(Qb, Kb, Vb, ctx);
  // dense GEMM: 32 x 32 tiles; regions 16 x 8 per XCD
  gemm128<4096, 4096, 4096, 8, 0><<<dim3(1024), 256, 0, stream>>>(
      ctx, Wd, out, nullptr, nullptr, nullptr, nullptr);
}

// Round 8
// 510.880 us; speedup vs baseline: 1.2856x; 1.0287x over previous
//
#include <hip/hip_runtime.h>
#include <hip/hip_bf16.h>
#include <stdint.h>

#define Bb 2
#define Ss 2048
#define Hh 4096
#define NHh 32
#define HDd 128
#define KVHh 2

typedef __attribute__((ext_vector_type(8))) short bf16x8;
typedef __attribute__((ext_vector_type(4))) float f32x4;
typedef __attribute__((ext_vector_type(16))) float f32x16;
typedef __attribute__((ext_vector_type(4))) unsigned int u32x4;
typedef unsigned short u16;
typedef unsigned int u32;
typedef unsigned long long u64;

__device__ __forceinline__ u16 f2b(float f) {
  union { float f; u32 u; } v; v.f = f;
  u32 r = v.u + 0x7fffu + ((v.u >> 16) & 1u);
  return (u16)(r >> 16);
}
__device__ __forceinline__ float b2f(u16 h) {
  union { u32 u; float f; } v; v.u = ((u32)h) << 16;
  return v.f;
}

__device__ __forceinline__ u32 cvtpk(float lo, float hi_) {
  u32 r;
  asm("v_cvt_pk_bf16_f32 %0, %1, %2" : "=v"(r) : "v"(lo), "v"(hi_));
  return r;
}
__device__ __forceinline__ void plswap(u32& x, u32& y) {
  asm volatile("v_permlane32_swap_b32 %0, %1" : "+v"(x), "+v"(y));
}

// async global->LDS, 16B per lane; LDS dest is wave-uniform base + lane*16
__device__ __forceinline__ void gload_lds16(const u16* g, u16* l) {
  __builtin_amdgcn_global_load_lds(
      (const __attribute__((address_space(1))) u32*)(uintptr_t)g,
      (__attribute__((address_space(3))) u32*)(u32)(uintptr_t)l,
      16, 0, 0);
}

// ---------------- f32 -> bf16 convert (vectorized) ----------------
__global__ void cvt_k(const float* __restrict__ in, u16* __restrict__ out, int n) {
  int i = blockIdx.x * blockDim.x + threadIdx.x;
  int idx = i * 4;
  if (idx >= n) return;
  float4 v = *(const float4*)&in[idx];
  u64 pack = (u64)f2b(v.x) | ((u64)f2b(v.y) << 16) |
             ((u64)f2b(v.z) << 32) | ((u64)f2b(v.w) << 48);
  *(u64*)&out[idx] = pack;
}

// ---------------- RoPE in-place on (B, nheads, S, HD) bf16 ----------------
__global__ void rope_k(u16* __restrict__ X, const float* __restrict__ rope, int nheads) {
  int i = blockIdx.x * blockDim.x + threadIdx.x;
  int p = i & 31;
  int s = (i >> 5) & (Ss - 1);
  int bh = i >> 16;
  if (bh >= Bb * nheads) return;
  int b = bh / nheads;
  size_t base = ((size_t)bh * Ss + s) * HDd + p * 2;
  u32 x01 = *(u32*)&X[base];
  float x0 = b2f((u16)(x01 & 0xffff));
  float x1 = b2f((u16)(x01 >> 16));
  float2 rc = *(const float2*)&rope[(((size_t)b * Ss + s) * 32 + p) * 2];
  float o0 = x0 * rc.x - x1 * rc.y;
  float o1 = x1 * rc.x + x0 * rc.y;
  u32 o = (u32)f2b(o0) | ((u32)f2b(o1) << 16);
  *(u32*)&X[base] = o;
}

// ---------------- 256x128 tile GEMM, BK=32, 8 waves, counted-vmcnt dbuf ----------------
// Tile 256(M)x128(N): arithmetic intensity 85 FLOP/B (vs 64 at 128^2) -> L2-demand
// at full MFMA rate drops from 32 TB/s to 24 TB/s. LDS 48KB dbuf -> 2 blocks/CU,
// 16 waves/CU; independent barrier groups hide latency (R5-proven mechanism).
// Staging = 3 gload_lds/thread (A:2, B:1); vmcnt(3) = next tile in flight.
// Swizzle: 16B-chunk c' = c ^ ((row>>1)&3) on BOTH stage-source and ds_read.
// XCD region map: each XCD owns an 8-rowtile x COLG-coltile region (square-ish
// working set minimizes L2-miss traffic; R7-proven: FETCH 636->274 MB).
template <int KK>
__device__ __forceinline__ void stage_tileA(const u16* __restrict__ gbase, u16* dst, int tid) {
#pragma unroll
  for (int li = 0; li < 2; ++li) {
    int t16 = li * 512 + tid;
    int rt = t16 >> 2, ct = t16 & 3;
    int cg = ct ^ ((rt >> 1) & 3);
    gload_lds16(gbase + (size_t)rt * KK + cg * 8, dst + t16 * 8);
  }
}
template <int KK>
__device__ __forceinline__ void stage_tileB(const u16* __restrict__ gbase, u16* dst, int tid) {
  int t16 = tid;
  int rt = t16 >> 2, ct = t16 & 3;
  int cg = ct ^ ((rt >> 1) & 3);
  gload_lds16(gbase + (size_t)rt * KK + cg * 8, dst + t16 * 8);
}

__device__ __forceinline__ bf16x8 frag128(const u16* buf, int row, int lk) {
  int ch = lk ^ ((row >> 1) & 3);
  return *(const bf16x8*)&buf[row * 32 + ch * 8];
}

template <int NN, int KK, int COLG, int EPI>
__global__ __launch_bounds__(512, 4) void gemm256x128(
    const u16* __restrict__ A, const u16* __restrict__ Bm,
    float* __restrict__ Cout, const float* __restrict__ bias,
    u16* __restrict__ Qb, u16* __restrict__ Kb, u16* __restrict__ Vb) {
  __shared__ u16 As[2][8192];
  __shared__ u16 Bs[2][4096];
  const int tid = threadIdx.x;
  const int wave = tid >> 6;
  const int lane = tid & 63;
  const int lr = lane & 15;
  const int lk = lane >> 4;
  const int wr = wave >> 1;           // 0..3 (M)
  const int wc = wave & 1;            // 0..1 (N)
  // XCD-region map: region = 8 rowtiles x COLG coltiles, row-major inside
  const int bid = blockIdx.x;
  const int xcd = bid & 7;
  const int local = bid >> 3;
  const int rlr = local / COLG;
  const int rlc = local - rlr * COLG;
  const int m0 = ((xcd >> 2) * 8 + rlr) * 256;
  const int n0 = ((xcd & 3) * COLG + rlc) * 128;
  const int NT = KK / 32;

  f32x4 acc[4][4];
#pragma unroll
  for (int i = 0; i < 4; ++i)
#pragma unroll
    for (int j = 0; j < 4; ++j) acc[i][j] = (f32x4){0.f, 0.f, 0.f, 0.f};

  const u16* Ab = A + (size_t)m0 * KK;
  const u16* Bb_ = Bm + (size_t)n0 * KK;

  stage_tileA<KK>(Ab, &As[0][0], tid);
  stage_tileB<KK>(Bb_, &Bs[0][0], tid);
  asm volatile("s_waitcnt vmcnt(0)");
  __syncthreads();

  int cur = 0;
  for (int t = 0; t < NT; ++t) {
    if (t + 1 < NT) {
      stage_tileA<KK>(Ab + (t + 1) * 32, &As[cur ^ 1][0], tid);
      stage_tileB<KK>(Bb_ + (t + 1) * 32, &Bs[cur ^ 1][0], tid);
      asm volatile("s_waitcnt vmcnt(3)");   // tile t landed; t+1 stays in flight
    } else {
      asm volatile("s_waitcnt vmcnt(0)");
    }
    __builtin_amdgcn_s_barrier();
    __builtin_amdgcn_sched_barrier(0);

    bf16x8 af[4], bf[4];
#pragma unroll
    for (int mi = 0; mi < 4; ++mi)
      af[mi] = frag128(&As[cur][0], wr * 64 + mi * 16 + lr, lk);
#pragma unroll
    for (int ni = 0; ni < 4; ++ni)
      bf[ni] = frag128(&Bs[cur][0], wc * 64 + ni * 16 + lr, lk);
    asm volatile("s_waitcnt lgkmcnt(0)");
    __builtin_amdgcn_sched_barrier(0);
    __builtin_amdgcn_s_setprio(1);
#pragma unroll
    for (int mi = 0; mi < 4; ++mi)
#pragma unroll
      for (int ni = 0; ni < 4; ++ni)
        acc[mi][ni] = __builtin_amdgcn_mfma_f32_16x16x32_bf16(af[mi], bf[ni], acc[mi][ni], 0, 0, 0);
    __builtin_amdgcn_s_setprio(0);
    __builtin_amdgcn_s_barrier();
    cur ^= 1;
  }

  if constexpr (EPI == 0) {
#pragma unroll
    for (int mi = 0; mi < 4; ++mi)
#pragma unroll
      for (int ni = 0; ni < 4; ++ni) {
        int col = n0 + wc * 64 + ni * 16 + lr;
        int rowb = m0 + wr * 64 + mi * 16 + lk * 4;
#pragma unroll
        for (int j = 0; j < 4; ++j)
          Cout[(size_t)(rowb + j) * NN + col] = acc[mi][ni][j];
      }
  } else {
#pragma unroll
    for (int ni = 0; ni < 4; ++ni) {
      int n = n0 + wc * 64 + ni * 16 + lr;
      float bv = bias[n];
#pragma unroll
      for (int mi = 0; mi < 4; ++mi) {
        int mb = m0 + wr * 64 + mi * 16 + lk * 4;
#pragma unroll
        for (int j = 0; j < 4; ++j) {
          int m = mb + j;
          int bb = m >> 11;
          int ss = m & 2047;
          u16 hv = f2b(acc[mi][ni][j] + bv);
          if (n < 4096) {
            Qb[(((size_t)bb * NHh + (n >> 7)) * Ss + ss) * HDd + (n & 127)] = hv;
          } else if (n < 4352) {
            int idx2 = n - 4096;
            Kb[(((size_t)bb * KVHh + (idx2 >> 7)) * Ss + ss) * HDd + (idx2 & 127)] = hv;
          } else {
            int idx2 = n - 4352;
            Vb[(((size_t)bb * KVHh + (idx2 >> 7)) * Ss + ss) * HDd + (idx2 & 127)] = hv;
          }
        }
      }
    }
  }
}

// ---------------- causal GQA flash attention, 8-wave 32x32 swapped-QK^T ----------------
// grid (4, NH, B): block x processes q-tile PAIR {7-x, x} -> 36 KV-iters for EVERY
// block: perfect causal load balance, 256 blocks = 1/CU.
__global__ __launch_bounds__(512, 2) void attn_k(
    const u16* __restrict__ Qb, const u16* __restrict__ Kb,
    const u16* __restrict__ Vb, u16* __restrict__ Ctx) {
  __shared__ u16 Kt[2][64 * 128];
  __shared__ u16 Vt[2][128 * 64];
  const int tid = threadIdx.x;
  const int w = tid >> 6;
  const int lane = tid & 63;
  const int l31 = lane & 31;
  const int hi = lane >> 5;
  const int h = blockIdx.y, b = blockIdx.z;
  const int hkv = h >> 4;
  const u16* Qp = Qb + ((size_t)(b * NHh + h)) * Ss * HDd;
  const u16* Kp = Kb + ((size_t)(b * KVHh + hkv)) * Ss * HDd;
  const u16* Vp = Vb + ((size_t)(b * KVHh + hkv)) * Ss * HDd;

  const float scale = 0.08838834764831845f;
  const float L2E = 1.4426950408889634f;

  for (int hp = 0; hp < 2; ++hp) {
    const int qt = hp == 0 ? (7 - (int)blockIdx.x) : (int)blockIdx.x;
    const int qs = qt * 256;
    const int qw = qs + w * 32;
    const int qrow = qw + l31;
    const int nt = qs / 64 + 4;

    bf16x8 qf[8];
#pragma unroll
    for (int ds = 0; ds < 8; ++ds)
      qf[ds] = *(const bf16x8*)&Qp[(size_t)qrow * HDd + ds * 16 + hi * 8];

    f32x16 accO[4];
#pragma unroll
    for (int i = 0; i < 4; ++i)
#pragma unroll
      for (int r = 0; r < 16; ++r) accO[i][r] = 0.f;
    float m_r = -3.0e38f, l_r = 0.f;

    {
#pragma unroll
      for (int i = 0; i < 2; ++i) {
        int slot = w * 2 + i;
        int r = slot * 4 + (lane >> 4);
        int p = lane & 15;
        int gc = (p & 8) | ((p ^ r) & 7);
        gload_lds16(Kp + (size_t)r * HDd + gc * 8, &Kt[0][slot * 512]);
      }
      bf16x8 v0 = *(const bf16x8*)&Vp[(size_t)lane * HDd + w * 16];
      bf16x8 v1 = *(const bf16x8*)&Vp[(size_t)lane * HDd + w * 16 + 8];
      u32x4 sv = __builtin_bit_cast(u32x4, (lane & 1) ? v0 : v1);
      u32x4 rv;
      rv.x = __shfl_xor(sv.x, 1); rv.y = __shfl_xor(sv.y, 1);
      rv.z = __shfl_xor(sv.z, 1); rv.w = __shfl_xor(sv.w, 1);
      bf16x8 recv = __builtin_bit_cast(bf16x8, rv);
      int kvp = lane >> 1;
#pragma unroll
      for (int i = 0; i < 8; ++i) {
        int d = w * 16 + (lane & 1) * 8 + i;
        u16 lo = (lane & 1) ? (u16)recv[i] : (u16)v0[i];
        u16 hb = (lane & 1) ? (u16)v1[i] : (u16)recv[i];
        u32 val = (u32)lo | ((u32)hb << 16);
        int cp = (kvp >> 2) ^ (d & 7);
        *(u32*)&Vt[0][d * 64 + cp * 8 + (kvp & 3) * 2] = val;
      }
    }
    __syncthreads();

    for (int t = 0; t < nt; ++t) {
      const int j0 = t * 64;
      const int cur = t & 1;
      const bool havenext = (t + 1 < nt);
      bf16x8 nv0, nv1;
      if (havenext) {
        const int j1 = j0 + 64;
#pragma unroll
        for (int i = 0; i < 2; ++i) {
          int slot = w * 2 + i;
          int r = slot * 4 + (lane >> 4);
          int p = lane & 15;
          int gc = (p & 8) | ((p ^ r) & 7);
          gload_lds16(Kp + (size_t)(j1 + r) * HDd + gc * 8, &Kt[cur ^ 1][slot * 512]);
        }
        nv0 = *(const bf16x8*)&Vp[(size_t)(j1 + lane) * HDd + w * 16];
        nv1 = *(const bf16x8*)&Vp[(size_t)(j1 + lane) * HDd + w * 16 + 8];
      }

      if (j0 <= qw + 31) {
        f32x16 aS[2];
#pragma unroll
        for (int a = 0; a < 2; ++a)
#pragma unroll
          for (int r = 0; r < 16; ++r) aS[a][r] = 0.f;
#pragma unroll
        for (int kvb = 0; kvb < 2; ++kvb) {
          int r = kvb * 32 + l31;
#pragma unroll
          for (int ds = 0; ds < 8; ++ds) {
            int c = ds * 2 + hi;
            int cp = (c & 8) | ((c ^ r) & 7);
            bf16x8 kf = *(const bf16x8*)&Kt[cur][r * 128 + cp * 8];
            aS[kvb] = __builtin_amdgcn_mfma_f32_32x32x16_bf16(kf, qf[ds], aS[kvb], 0, 0, 0);
          }
        }
        const bool needmask = (j0 + 63 > qw);
        float mx = -3.0e38f;
#pragma unroll
        for (int a = 0; a < 2; ++a)
#pragma unroll
          for (int r = 0; r < 16; ++r) {
            float s = aS[a][r] * scale;
            if (needmask) {
              int kv = j0 + a * 32 + (r & 3) + 8 * (r >> 2) + 4 * hi;
              s = (kv > qrow) ? -3.0e38f : s;
            }
            aS[a][r] = s;
            mx = fmaxf(mx, s);
          }
        mx = fmaxf(mx, __shfl_xor(mx, 32));
        float mnew = fmaxf(m_r, mx);
        float corr = __builtin_amdgcn_exp2f((m_r - mnew) * L2E);
        float sum = 0.f;
#pragma unroll
        for (int a = 0; a < 2; ++a)
#pragma unroll
          for (int r = 0; r < 16; ++r) {
            float pe = __builtin_amdgcn_exp2f((aS[a][r] - mnew) * L2E);
            aS[a][r] = pe;
            sum += pe;
          }
        sum += __shfl_xor(sum, 32);
        l_r = l_r * corr + sum;
        m_r = mnew;
#pragma unroll
        for (int i = 0; i < 4; ++i)
#pragma unroll
          for (int r = 0; r < 16; ++r) accO[i][r] *= corr;

        u32 cc0[2][4], cc1[2][4];
#pragma unroll
        for (int a = 0; a < 2; ++a)
#pragma unroll
          for (int g = 0; g < 4; ++g) {
            cc0[a][g] = cvtpk(aS[a][g * 4 + 0], aS[a][g * 4 + 1]);
            cc1[a][g] = cvtpk(aS[a][g * 4 + 2], aS[a][g * 4 + 3]);
          }
        bf16x8 pa[4];
#pragma unroll
        for (int ks = 0; ks < 4; ++ks) {
          int a = ks >> 1, g0 = (ks & 1) * 2;
          u32 w0 = cc0[a][g0], w2 = cc0[a][g0 + 1];
          u32 w1 = cc1[a][g0], w3 = cc1[a][g0 + 1];
          plswap(w0, w2);
          plswap(w1, w3);
          u32x4 tv; tv.x = w0; tv.y = w1; tv.z = w2; tv.w = w3;
          pa[ks] = __builtin_bit_cast(bf16x8, tv);
        }
#pragma unroll
        for (int dblk = 0; dblk < 4; ++dblk) {
          int d = dblk * 32 + l31;
#pragma unroll
          for (int ks = 0; ks < 4; ++ks) {
            int c = ks * 2 + hi;
            int cp = c ^ (d & 7);
            bf16x8 vf = *(const bf16x8*)&Vt[cur][d * 64 + cp * 8];
            accO[dblk] = __builtin_amdgcn_mfma_f32_32x32x16_bf16(vf, pa[ks], accO[dblk], 0, 0, 0);
          }
        }
      }

      if (havenext) {
        u32x4 sv = __builtin_bit_cast(u32x4, (lane & 1) ? nv0 : nv1);
        u32x4 rv;
        rv.x = __shfl_xor(sv.x, 1); rv.y = __shfl_xor(sv.y, 1);
        rv.z = __shfl_xor(sv.z, 1); rv.w = __shfl_xor(sv.w, 1);
        bf16x8 recv = __builtin_bit_cast(bf16x8, rv);
        int kvp = lane >> 1;
#pragma unroll
        for (int i = 0; i < 8; ++i) {
          int d = w * 16 + (lane & 1) * 8 + i;
          u16 lo = (lane & 1) ? (u16)recv[i] : (u16)nv0[i];
          u16 hb = (lane & 1) ? (u16)nv1[i] : (u16)recv[i];
          u32 val = (u32)lo | ((u32)hb << 16);
          int cp = (kvp >> 2) ^ (d & 7);
          *(u32*)&Vt[cur ^ 1][d * 64 + cp * 8 + (kvp & 3) * 2] = val;
        }
      }
      __syncthreads();
    }

    {
      float il = 1.0f / l_r;
      size_t rb = ((size_t)b * Ss + qrow) * (size_t)(NHh * HDd) + (size_t)h * HDd;
#pragma unroll
      for (int dblk = 0; dblk < 4; ++dblk)
#pragma unroll
        for (int g = 0; g < 4; ++g) {
          int d0 = dblk * 32 + g * 8 + hi * 4;
          u64 pack = (u64)f2b(accO[dblk][g * 4 + 0] * il) |
                     ((u64)f2b(accO[dblk][g * 4 + 1] * il) << 16) |
                     ((u64)f2b(accO[dblk][g * 4 + 2] * il) << 32) |
                     ((u64)f2b(accO[dblk][g * 4 + 3] * il) << 48);
          *(u64*)&Ctx[rb + d0] = pack;
        }
    }
    __syncthreads();
  }
}

extern "C" void kernel_launch(void* const* d_in, const int* in_sizes, int n_in,
                              void* d_out, int out_size, void* d_ws, size_t ws_size,
                              hipStream_t stream) {
  const float* hidden = (const float*)d_in[0];
  const float* rope = (const float*)d_in[1];
  const float* Wqkv = (const float*)d_in[3];
  const float* bqkv = (const float*)d_in[4];
  const float* Wdense = (const float*)d_in[5];
  float* out = (float*)d_out;

  char* w = (char*)d_ws;
  u16* Xbf = (u16*)w;
  u16* ctx = Xbf;
  w += (size_t)33554432;
  u16* Wq = (u16*)w;
  u16* Wd = Wq;
  w += (size_t)37748736;
  u16* Qb = (u16*)w; w += (size_t)33554432;
  u16* Kb = (u16*)w; w += (size_t)2097152;
  u16* Vb = (u16*)w; w += (size_t)2097152;

  cvt_k<<<(16777216 / 4 + 255) / 256, 256, 0, stream>>>(hidden, Xbf, 16777216);
  cvt_k<<<(18874368 / 4 + 255) / 256, 256, 0, stream>>>(Wqkv, Wq, 18874368);
  // QKV GEMM: 16 x 36 tiles (256x128) = 576 blocks; regions 8 x 9 per XCD
  gemm256x128<4608, 4096, 9, 1><<<dim3(576), 512, 0, stream>>>(
      Xbf, Wq, nullptr, bqkv, Qb, Kb, Vb);
  rope_k<<<(Bb * NHh * Ss * 32 + 255) / 256, 256, 0, stream>>>(Qb, rope, NHh);
  rope_k<<<(Bb * KVHh * Ss * 32 + 255) / 256, 256, 0, stream>>>(Kb, rope, KVHh);
  cvt_k<<<(16777216 / 4 + 255) / 256, 256, 0, stream>>>(Wdense, Wd, 16777216);
  // balanced causal pairing: grid (4, NH, B)
  attn_k<<<dim3(4, NHh, Bb), 512, 0, stream>>>(Qb, Kb, Vb, ctx);
  // dense GEMM: 16 x 32 tiles (256x128) = 512 blocks; regions 8 x 8 per XCD
  gemm256x128<4096, 4096, 8, 0><<<dim3(512), 512, 0, stream>>>(
      ctx, Wd, out, nullptr, nullptr, nullptr, nullptr);
}